// Round 16
// baseline (28.644 us; speedup 1.0000x reference)
//
#include <hip/hip_runtime.h>
#include <hip/hip_bf16.h>
#include <hip/hip_fp16.h>

// Problem constants
#define NQ 2048
#define NP 256
#define H1 128
#define H2 64

typedef __attribute__((ext_vector_type(8))) _Float16 f16x8;
typedef __attribute__((ext_vector_type(2))) __fp16   h16x2;
typedef __attribute__((ext_vector_type(4))) float    f32x4;

// Workspace BYTE layout:
#define WB_PH   0         //  65536: ph16 [256][128] f16 swizzled image
#define WB_W2   65536     //  16384: w216 [64][128] f16 swizzled image
#define WB_QH   81920     // 524288: qh16 [2048][128] f16 linear (b1 folded)
#define WB_BASE 606208    // 2097152: baseM [2048][256] f32

static __device__ __forceinline__ f16x8 cvt8(float4 a, float4 b) {
    f16x8 f;
    f[0] = (_Float16)a.x; f[1] = (_Float16)a.y;
    f[2] = (_Float16)a.z; f[3] = (_Float16)a.w;
    f[4] = (_Float16)b.x; f[5] = (_Float16)b.y;
    f[6] = (_Float16)b.z; f[7] = (_Float16)b.w;
    return f;
}
// 16B fragment read from a 256B-row f16 LDS array, XOR-swizzled
#define FRAG(base, row, ks) \
    (*(const f16x8*)((base) + ((((row) * 256 + (ks) * 64 + g * 16)) ^ (((row) & 7) << 4))))

// ---------------------------------------------------------------------------
// PREP (grid 208 x 256 thr, single round, all loads coalesced):
//  bx  0..63 : q-proj, 32 q rows each. Stage W1q half -> LDS f16 swz, MFMA
//              D[h][q], write qh16 linear with b1 folded (packed uint2).
//  bx 64..79 : p-proj, 16 p cols each + 1/16 slice of W2 cast. Stage W1p
//              half -> LDS; MFMA D[h][p]; write pre-swizzled ph16 image.
//  bx 80..207: base tiles 16q x 256p -> baseM (R12-verified code).
// ---------------------------------------------------------------------------
__global__ void __launch_bounds__(256)
prep_kernel(const float* __restrict__ q, const float* __restrict__ p,
            const float* __restrict__ W1, const float* __restrict__ b1,
            const float* __restrict__ W2, char* __restrict__ wsb) {
    __shared__ char w1_s[32768];
    int bx = blockIdx.x, tid = threadIdx.x;
    int lane = tid & 63, w = tid >> 6, lo = lane & 15, g = lane >> 4;
    const f32x4 Zv = (f32x4){0.f, 0.f, 0.f, 0.f};

    if (bx < 80) {
        // ---- stage W1 half (q-half for bx<64, p-half else), coalesced ----
        int woff = (bx < 64) ? 0 : 128;
        #pragma unroll
        for (int it = 0; it < 8; ++it) {
            int o = it * 256 + tid;            // octet 0..2047
            int row = o >> 4;
            const float* src = W1 + row * 256 + woff + (o & 15) * 8;
            *(f16x8*)(w1_s + ((o * 16) ^ ((row & 7) << 4))) =
                cvt8(*(const float4*)src, *(const float4*)(src + 4));
        }
        if (bx >= 64 && tid < 64) {            // W2 slice cast (4 rows)
            int rw = (bx - 64) * 4 + (tid >> 4);
            int c = tid & 15;
            const float* src = W2 + rw * 128 + c * 8;
            *(f16x8*)(wsb + WB_W2 + ((rw * 256 + c * 16) ^ ((rw & 7) << 4))) =
                cvt8(*(const float4*)src, *(const float4*)(src + 4));
        }
        __syncthreads();

        if (bx < 64) {                         // ---- q-proj: 32 q rows ----
            int r0 = bx * 32;
            f16x8 Aw[2][4];
            #pragma unroll
            for (int n = 0; n < 2; ++n)
                #pragma unroll
                for (int ks = 0; ks < 4; ++ks)
                    Aw[n][ks] = FRAG(w1_s, w * 32 + n * 16 + lo, ks);
            float4 b1v[2];
            b1v[0] = *(const float4*)(b1 + w * 32 + g * 4);
            b1v[1] = *(const float4*)(b1 + w * 32 + 16 + g * 4);
            #pragma unroll
            for (int half = 0; half < 2; ++half) {
                int qrow = r0 + half * 16 + lo;
                f16x8 Bq[4];
                #pragma unroll
                for (int ks = 0; ks < 4; ++ks) {
                    const float* src = q + qrow * 128 + ks * 32 + g * 8;
                    Bq[ks] = cvt8(*(const float4*)src, *(const float4*)(src + 4));
                }
                #pragma unroll
                for (int n = 0; n < 2; ++n) {
                    f32x4 C = Zv;
                    #pragma unroll
                    for (int ks = 0; ks < 4; ++ks)
                        C = __builtin_amdgcn_mfma_f32_16x16x32_f16(Aw[n][ks], Bq[ks], C, 0, 0, 0);
                    union { h16x2 h[2]; uint2 v; } pk;
                    pk.h[0] = __builtin_amdgcn_cvt_pkrtz(C[0] + b1v[n].x, C[1] + b1v[n].y);
                    pk.h[1] = __builtin_amdgcn_cvt_pkrtz(C[2] + b1v[n].z, C[3] + b1v[n].w);
                    *(uint2*)(wsb + WB_QH + qrow * 256 + (w * 32 + n * 16 + g * 4) * 2) = pk.v;
                }
            }
        } else {                               // ---- p-proj: 16 p cols ----
            int p0 = (bx - 64) * 16;
            f16x8 Bp[4];
            #pragma unroll
            for (int ks = 0; ks < 4; ++ks) {
                const float* src = p + (p0 + lo) * 128 + ks * 32 + g * 8;
                Bp[ks] = cvt8(*(const float4*)src, *(const float4*)(src + 4));
            }
            #pragma unroll
            for (int hi = 0; hi < 2; ++hi) {
                int ht = w * 2 + hi;
                f32x4 C = Zv;
                #pragma unroll
                for (int ks = 0; ks < 4; ++ks) {
                    f16x8 Ap = FRAG(w1_s, ht * 16 + lo, ks);
                    C = __builtin_amdgcn_mfma_f32_16x16x32_f16(Ap, Bp[ks], C, 0, 0, 0);
                }
                int pp = p0 + lo, h0 = ht * 16 + g * 4;
                union { h16x2 h[2]; uint2 v; } pk;
                pk.h[0] = __builtin_amdgcn_cvt_pkrtz(C[0], C[1]);
                pk.h[1] = __builtin_amdgcn_cvt_pkrtz(C[2], C[3]);
                *(uint2*)(wsb + WB_PH + ((pp * 256 + h0 * 2) ^ ((pp & 7) << 4))) = pk.v;
            }
        }
        return;
    }

    // ---- base tiles (R12-verified): q rows r0..r0+15, wave w p [64w,+64) ----
    float* baseM = (float*)(wsb + WB_BASE);
    int r0 = (bx - 80) * 16;

    float4 qr[4][2];
    #pragma unroll
    for (int ks = 0; ks < 4; ++ks) {
        const float* src = q + (r0 + lo) * 128 + ks * 32 + g * 8;
        qr[ks][0] = *(const float4*)src;
        qr[ks][1] = *(const float4*)(src + 4);
    }
    float4 pr_[4][4][2];
    #pragma unroll
    for (int n = 0; n < 4; ++n) {
        int pcol = w * 64 + n * 16 + lo;
        #pragma unroll
        for (int ks = 0; ks < 4; ++ks) {
            const float* src = p + pcol * 128 + ks * 32 + g * 8;
            pr_[n][ks][0] = *(const float4*)src;
            pr_[n][ks][1] = *(const float4*)(src + 4);
        }
    }
    f16x8 A[4];
    float asq = 0.f;
    #pragma unroll
    for (int ks = 0; ks < 4; ++ks) {
        float4 a = qr[ks][0], b = qr[ks][1];
        asq += a.x*a.x + a.y*a.y + a.z*a.z + a.w*a.w
             + b.x*b.x + b.y*b.y + b.z*b.z + b.w*b.w;
        A[ks] = cvt8(a, b);
    }
    asq += __shfl_xor(asq, 16);
    asq += __shfl_xor(asq, 32);

    f32x4 C[4];
    float psq[4];
    #pragma unroll
    for (int n = 0; n < 4; ++n) {
        C[n] = Zv;
        psq[n] = 0.f;
        #pragma unroll
        for (int ks = 0; ks < 4; ++ks) {
            float4 a = pr_[n][ks][0], b = pr_[n][ks][1];
            psq[n] += a.x*a.x + a.y*a.y + a.z*a.z + a.w*a.w
                    + b.x*b.x + b.y*b.y + b.z*b.z + b.w*b.w;
            C[n] = __builtin_amdgcn_mfma_f32_16x16x32_f16(A[ks], cvt8(a, b), C[n], 0, 0, 0);
        }
        psq[n] += __shfl_xor(psq[n], 16);
        psq[n] += __shfl_xor(psq[n], 32);
    }
    #pragma unroll
    for (int n = 0; n < 4; ++n) {
        int pcol = w * 64 + n * 16 + lo;
        #pragma unroll
        for (int r = 0; r < 4; ++r) {
            float qnv = __shfl(asq, g * 4 + r);
            baseM[(r0 + g * 4 + r) * NP + pcol] =
                fmaxf(qnv + psq[n] - 2.f * C[n][r], 0.f);
        }
    }
}

// ---------------------------------------------------------------------------
// CONSUMER (grid 1024 x 256 thr, 3 blocks/CU): block = 4 q x 128 p.
// Stages only 49 KB (ph-half + w2 + qh-tile) as PURE copies; wave w owns
// 32 p (2 n-tiles -> P = 32 VGPR). n-tiles processed sequentially (C = 16
// VGPR) -> ~165 VGPR -> 3 waves/SIMD; 3 independent blocks/CU overlap
// staging/compute phases across blocks.
// ---------------------------------------------------------------------------
__global__ void __launch_bounds__(256, 3)
mlp_kernel(const char* __restrict__ wsb,
           const float* __restrict__ b2, const float* __restrict__ w3,
           const float* __restrict__ b3, float* __restrict__ out) {
    __shared__ char ph_s[32768];
    __shared__ char w2_s[16384];
    __shared__ char qh_s[1024];
    int tid = threadIdx.x, lane = tid & 63, w = tid >> 6;   // w 0..3
    int lo = lane & 15, g = lane >> 4;
    int bx = blockIdx.x;
    int q0 = (bx >> 1) * 4, bp = bx & 1;

    // pure-copy staging (no cvt): ph-half 32KB, w2 16KB, qh-tile 1KB
    const char* phsrc = wsb + WB_PH + bp * 32768;
    #pragma unroll
    for (int it = 0; it < 8; ++it) {
        int i16 = (it * 256 + tid) * 16;
        *(uint4*)(ph_s + i16) = *(const uint4*)(phsrc + i16);
    }
    const char* w2src = wsb + WB_W2;
    #pragma unroll
    for (int it = 0; it < 4; ++it) {
        int i16 = (it * 256 + tid) * 16;
        *(uint4*)(w2_s + i16) = *(const uint4*)(w2src + i16);
    }
    if (tid < 64)
        *(uint4*)(qh_s + tid * 16) =
            *(const uint4*)(wsb + WB_QH + q0 * 256 + tid * 16);
    __syncthreads();

    // P frags: wave's 32 p (2 n-tiles)
    f16x8 P[2][4];
    #pragma unroll
    for (int nt = 0; nt < 2; ++nt)
        #pragma unroll
        for (int ks = 0; ks < 4; ++ks) {
            P[nt][ks] = FRAG(ph_s, w * 32 + nt * 16 + lo, ks);
            asm volatile("" : "+v"(P[nt][ks]));
        }
    // Af frags
    f16x8 Af[4][4];
    #pragma unroll
    for (int m = 0; m < 4; ++m)
        #pragma unroll
        for (int ks = 0; ks < 4; ++ks) {
            Af[m][ks] = FRAG(w2_s, m * 16 + lo, ks);
            asm volatile("" : "+v"(Af[m][ks]));
        }

    h16x2 b2p[4][2], w3p[4][2];
    #pragma unroll
    for (int m = 0; m < 4; ++m) {
        float4 bb = *(const float4*)(b2 + m * 16 + g * 4);
        float4 ww = *(const float4*)(w3 + m * 16 + g * 4);
        b2p[m][0] = __builtin_amdgcn_cvt_pkrtz(bb.x, bb.y);
        b2p[m][1] = __builtin_amdgcn_cvt_pkrtz(bb.z, bb.w);
        w3p[m][0] = __builtin_amdgcn_cvt_pkrtz(ww.x, ww.y);
        w3p[m][1] = __builtin_amdgcn_cvt_pkrtz(ww.z, ww.w);
    }
    float b3v = b3[0];
    const f16x8 zz = {};
    const h16x2 z2 = {};
    const f32x4 Zv = (f32x4){0.f, 0.f, 0.f, 0.f};
    const float* baseM = (const float*)(wsb + WB_BASE);
    int pmine = bp * 128 + w * 32 + (g & 1) * 16 + lo;   // lane's own p

    #pragma unroll
    for (int qq = 0; qq < 4; ++qq) {
        float bse = baseM[(q0 + qq) * NP + pmine];
        f16x8 qk[4];
        #pragma unroll
        for (int ks = 0; ks < 4; ++ks)
            qk[ks] = *(const f16x8*)(qh_s + qq * 256 + ks * 64 + g * 16);

        float zp[2];
        #pragma unroll
        for (int nt = 0; nt < 2; ++nt) {
            f32x4 C[4];
            #pragma unroll
            for (int ks = 0; ks < 4; ++ks) {
                f16x8 B = __builtin_elementwise_max(P[nt][ks] + qk[ks], zz);
                #pragma unroll
                for (int m = 0; m < 4; ++m)
                    C[m] = __builtin_amdgcn_mfma_f32_16x16x32_f16(
                        Af[m][ks], B, (ks == 0) ? Zv : C[m], 0, 0, 0);
            }
            float sA = 0.f, sB = 0.f;
            #pragma unroll
            for (int m = 0; m < 4; ++m) {
                h16x2 c01 = __builtin_amdgcn_cvt_pkrtz(C[m][0], C[m][1]);
                h16x2 c23 = __builtin_amdgcn_cvt_pkrtz(C[m][2], C[m][3]);
                h16x2 h01 = __builtin_elementwise_max(c01 + b2p[m][0], z2);
                h16x2 h23 = __builtin_elementwise_max(c23 + b2p[m][1], z2);
                sA = __builtin_amdgcn_fdot2(h01, w3p[m][0], sA, false);
                sB = __builtin_amdgcn_fdot2(h23, w3p[m][1], sB, false);
            }
            zp[nt] = sA + sB;
        }
        // cross-lane reduce (both nt together, ILP)
        float sh[2];
        #pragma unroll
        for (int i = 0; i < 2; ++i) sh[i] = __shfl_xor(zp[i], 16);
        #pragma unroll
        for (int i = 0; i < 2; ++i) zp[i] += sh[i];
        #pragma unroll
        for (int i = 0; i < 2; ++i) sh[i] = __shfl_xor(zp[i], 32);
        #pragma unroll
        for (int i = 0; i < 2; ++i) zp[i] += sh[i];

        float z = ((g & 1) == 0) ? zp[0] : zp[1];
        z += b3v;
        float sp = fmaxf(z, 0.f) + __logf(1.f + __expf(-fabsf(z)));
        if (g < 2)
            out[(q0 + qq) * NP + pmine] = bse * (1.f + sp);   // cw ~= alpha
    }
}

extern "C" void kernel_launch(void* const* d_in, const int* in_sizes, int n_in,
                              void* d_out, int out_size, void* d_ws, size_t ws_size,
                              hipStream_t stream) {
    const float* q  = (const float*)d_in[0];
    const float* pr = (const float*)d_in[1];
    const float* W1 = (const float*)d_in[2];
    const float* b1 = (const float*)d_in[3];
    const float* W2 = (const float*)d_in[4];
    const float* b2 = (const float*)d_in[5];
    const float* W3 = (const float*)d_in[6];
    const float* b3 = (const float*)d_in[7];
    float* out = (float*)d_out;
    char* wsb  = (char*)d_ws;

    prep_kernel<<<208, 256, 0, stream>>>(q, pr, W1, b1, W2, wsb);
    mlp_kernel<<<1024, 256, 0, stream>>>(wsb, b2, W3, b3, out);
}

// Round 17
// 21.622 us; speedup vs baseline: 1.3248x; 1.3248x over previous
//
#include <hip/hip_runtime.h>
#include <hip/hip_bf16.h>
#include <hip/hip_fp16.h>

// Problem constants
#define D1   128
#define NQ   2048
#define NP   256
#define H1   128
#define H2   64

typedef __attribute__((ext_vector_type(8))) _Float16 f16x8;
typedef __attribute__((ext_vector_type(2))) __fp16   h16x2;
typedef __attribute__((ext_vector_type(4))) float    f32x4;

// LDS layout (bytes). pf16 (raw p, f16) is consumed into regs in phase 1,
// then ALIASED as ph (projected p) -- barrier-separated.
#define L_PF   0          // [256][128] f16 swz   65536 B   (later ph [p][h])
#define L_W1Q  65536      // [128][128] f16 swz   32768 B
#define L_W1P  98304      // [128][128] f16 swz   32768 B
#define L_W2   131072     // [ 64][128] f16 swz   16384 B
#define L_QF   147456     // [  8][128] f16 swz    2048 B
#define L_QH   149504     // [  8][128] f16 lin    2048 B
#define LDS_TOTAL 151552

static __device__ __forceinline__ f16x8 cvt8(float4 a, float4 b) {
    f16x8 f;
    f[0] = (_Float16)a.x; f[1] = (_Float16)a.y;
    f[2] = (_Float16)a.z; f[3] = (_Float16)a.w;
    f[4] = (_Float16)b.x; f[5] = (_Float16)b.y;
    f[6] = (_Float16)b.z; f[7] = (_Float16)b.w;
    return f;
}
static __device__ __forceinline__ float sqsum8(f16x8 v, float acc) {
    union { f16x8 f; h16x2 h[4]; } u; u.f = v;
    acc = __builtin_amdgcn_fdot2(u.h[0], u.h[0], acc, false);
    acc = __builtin_amdgcn_fdot2(u.h[1], u.h[1], acc, false);
    acc = __builtin_amdgcn_fdot2(u.h[2], u.h[2], acc, false);
    acc = __builtin_amdgcn_fdot2(u.h[3], u.h[3], acc, false);
    return acc;
}
// 16B fragment read from a 256B-row f16 LDS array, XOR-swizzled
#define FRAG(base, row, ks) \
    (*(const f16x8*)((base) + ((((row) * 256 + (ks) * 64 + g * 16)) ^ (((row) & 7) << 4))))

// ---------------------------------------------------------------------------
// ONE kernel, 512 threads, grid 256 (1 block/CU), block = 8 q x 256 p.
// Wave w: p-range (w&3)*64, q-half & h-tile-half (w>>2).
// R14 + one change: W1/W2 staging issues CONCURRENT with dist/norm compute
// (both independent), hiding the 176KB staging latency under ~20 MFMA +
// ~200 VALU of distance work instead of serializing phase-0 before all
// compute. Everything else identical to R14 (22.4 us best).
// ---------------------------------------------------------------------------
__global__ void __launch_bounds__(512, 2)
fused_kernel(const float* __restrict__ q, const float* __restrict__ p,
             const float* __restrict__ W1, const float* __restrict__ b1,
             const float* __restrict__ W2, const float* __restrict__ b2,
             const float* __restrict__ w3, const float* __restrict__ b3,
             float* __restrict__ out) {
    extern __shared__ char lds[];
    char* pf_s  = lds + L_PF;
    char* w1q_s = lds + L_W1Q;
    char* w1p_s = lds + L_W1P;
    char* w2_s  = lds + L_W2;
    char* qf_s  = lds + L_QF;
    char* qh_s  = lds + L_QH;

    int tid = threadIdx.x, lane = tid & 63, w = tid >> 6;   // w 0..7
    int lo = lane & 15, g = lane >> 4;
    int wp = w & 3, qh2 = w >> 2;
    int q0 = blockIdx.x * 8;

    // ---------------- phase 0a: stage p + q (coalesced) ----------------
    #pragma unroll
    for (int it = 0; it < 8; ++it) {        // p: [256][128] f32, 32768 f32
        int j8 = (it * 512 + tid) * 8;
        int row = j8 >> 7;
        const float* src = p + j8;
        *(f16x8*)(pf_s + ((j8 * 2) ^ ((row & 7) << 4))) =
            cvt8(*(const float4*)src, *(const float4*)(src + 4));
    }
    if (tid < 128) {                        // q rows q0..q0+7: 1024 f32
        int j8 = tid * 8;
        int row = j8 >> 7;
        const float* src = q + q0 * D1 + j8;
        *(f16x8*)(qf_s + ((j8 * 2) ^ ((row & 7) << 4))) =
            cvt8(*(const float4*)src, *(const float4*)(src + 4));
    }
    __syncthreads();                        // p, q staged

    // ---------------- phase 0b ∥ 1a: stage W1/W2 while computing dist ----
    // (W1/W2 staging is independent of everything below until the barrier)
    #pragma unroll
    for (int it = 0; it < 8; ++it) {        // W1: [128][256] f32, split halves
        int j8 = (it * 512 + tid) * 8;
        int row = j8 >> 8, col = j8 & 255;
        const float* src = W1 + j8;
        f16x8 v = cvt8(*(const float4*)src, *(const float4*)(src + 4));
        char* base = (col < 128) ? w1q_s : w1p_s;
        *(f16x8*)(base + ((row * 256 + (col & 127) * 2) ^ ((row & 7) << 4))) = v;
    }
    #pragma unroll
    for (int it = 0; it < 2; ++it) {        // W2: [64][128] f32, 8192 f32
        int j8 = (it * 512 + tid) * 8;
        int row = j8 >> 7;
        const float* src = W2 + j8;
        *(f16x8*)(w2_s + ((j8 * 2) ^ ((row & 7) << 4))) =
            cvt8(*(const float4*)src, *(const float4*)(src + 4));
    }

    // fragment loads from already-staged p/q + norms + dist (no W1 dep)
    f16x8 Praw[4][4];
    float psq[4];
    #pragma unroll
    for (int n = 0; n < 4; ++n) {
        int prow = wp * 64 + n * 16 + lo;
        psq[n] = 0.f;
        #pragma unroll
        for (int ks = 0; ks < 4; ++ks) {
            Praw[n][ks] = FRAG(pf_s, prow, ks);
            psq[n] = sqsum8(Praw[n][ks], psq[n]);
        }
        psq[n] += __shfl_xor(psq[n], 16);
        psq[n] += __shfl_xor(psq[n], 32);   // pn[prow] on every lane
    }
    f16x8 Adist[4];
    float asq = 0.f;
    {
        int qrow = qh2 * 4 + (lo & 3);      // rows dup across g (R10 trick)
        #pragma unroll
        for (int ks = 0; ks < 4; ++ks) {
            Adist[ks] = FRAG(qf_s, qrow, ks);
            asq = sqsum8(Adist[ks], asq);
        }
        asq += __shfl_xor(asq, 16);
        asq += __shfl_xor(asq, 32);         // qn[qrow] on every lane
    }
    const f32x4 Zv = (f32x4){0.f, 0.f, 0.f, 0.f};
    const f16x8 zz = {};
    const h16x2 z2 = {};
    float bse[4];
    {   // dist: D[q][p]; lane's own p -> frag n=g
        f32x4 Cd[4];
        #pragma unroll
        for (int n = 0; n < 4; ++n) {
            Cd[n] = Zv;
            #pragma unroll
            for (int ks = 0; ks < 4; ++ks)
                Cd[n] = __builtin_amdgcn_mfma_f32_16x16x32_f16(Adist[ks], Praw[n][ks], Cd[n], 0, 0, 0);
        }
        float pnm = (g == 0) ? psq[0] : (g == 1) ? psq[1] : (g == 2) ? psq[2] : psq[3];
        #pragma unroll
        for (int qq = 0; qq < 4; ++qq) {
            float qn = __shfl(asq, qq);
            float dg = (g == 0) ? Cd[0][qq] : (g == 1) ? Cd[1][qq]
                     : (g == 2) ? Cd[2][qq] : Cd[3][qq];
            bse[qq] = fmaxf(qn + pnm - 2.f * dg, 0.f);
        }
    }
    // Bq (from qf_s, already staged) can load before the barrier too
    f16x8 Bq[4];
    {
        int qrow2 = lo & 7;
        #pragma unroll
        for (int ks = 0; ks < 4; ++ks)
            Bq[ks] = FRAG(qf_s, qrow2, ks);
    }
    float4 b1v = *(const float4*)(b1 + w * 16 + g * 4);
    __syncthreads();                        // W1/W2 staged; pf reads done

    // ---------------- phase 1b: q-proj, p-proj ----------------
    {   // q-proj: D[h = w*16+g*4+r][q = lo], write rows lo<8, b1 folded
        f16x8 Aq[4];
        int hrow = w * 16 + lo;
        #pragma unroll
        for (int ks = 0; ks < 4; ++ks)
            Aq[ks] = FRAG(w1q_s, hrow, ks);
        f32x4 Cq = Zv;
        #pragma unroll
        for (int ks = 0; ks < 4; ++ks)
            Cq = __builtin_amdgcn_mfma_f32_16x16x32_f16(Aq[ks], Bq[ks], Cq, 0, 0, 0);
        if (lo < 8) {
            union { h16x2 h[2]; uint2 v; } pk;
            pk.h[0] = __builtin_amdgcn_cvt_pkrtz(Cq[0] + b1v.x, Cq[1] + b1v.y);
            pk.h[1] = __builtin_amdgcn_cvt_pkrtz(Cq[2] + b1v.z, Cq[3] + b1v.w);
            *(uint2*)(qh_s + lo * 256 + w * 32 + g * 8) = pk.v;
        }
    }
    // p-proj: wave covers h-tiles qh2*4..+3 x own 4 p-tiles; write ph (=pf_s)
    #pragma unroll
    for (int hp = 0; hp < 2; ++hp) {
        f16x8 Ap[2][4];
        #pragma unroll
        for (int ht = 0; ht < 2; ++ht) {
            int h = (qh2 * 4 + hp * 2 + ht) * 16 + lo;
            #pragma unroll
            for (int ks = 0; ks < 4; ++ks)
                Ap[ht][ks] = FRAG(w1p_s, h, ks);
        }
        #pragma unroll
        for (int n = 0; n < 4; ++n) {
            f32x4 Cp0 = Zv, Cp1 = Zv;
            #pragma unroll
            for (int ks = 0; ks < 4; ++ks) {
                Cp0 = __builtin_amdgcn_mfma_f32_16x16x32_f16(Ap[0][ks], Praw[n][ks], Cp0, 0, 0, 0);
                Cp1 = __builtin_amdgcn_mfma_f32_16x16x32_f16(Ap[1][ks], Praw[n][ks], Cp1, 0, 0, 0);
            }
            int pp = wp * 64 + n * 16 + lo;
            #pragma unroll
            for (int ht = 0; ht < 2; ++ht) {
                f32x4 Cp = ht ? Cp1 : Cp0;
                int h0 = (qh2 * 4 + hp * 2 + ht) * 16 + g * 4;
                union { h16x2 h[2]; uint2 v; } pk;
                pk.h[0] = __builtin_amdgcn_cvt_pkrtz(Cp[0], Cp[1]);
                pk.h[1] = __builtin_amdgcn_cvt_pkrtz(Cp[2], Cp[3]);
                *(uint2*)(pf_s + ((pp * 256 + h0 * 2) ^ ((pp & 7) << 4))) = pk.v;
            }
        }
    }
    __syncthreads();                        // ph, qh ready

    // ---------------- phase 2: main MLP loop (R12/R14 body) ----------------
    f16x8 P[4][4];
    #pragma unroll
    for (int n = 0; n < 4; ++n)
        #pragma unroll
        for (int ks = 0; ks < 4; ++ks) {
            int pp = wp * 64 + n * 16 + lo;
            P[n][ks] = FRAG(pf_s, pp, ks);
            asm volatile("" : "+v"(P[n][ks]));
        }
    f16x8 Af[4][4];
    #pragma unroll
    for (int m = 0; m < 4; ++m)
        #pragma unroll
        for (int ks = 0; ks < 4; ++ks) {
            Af[m][ks] = FRAG(w2_s, m * 16 + lo, ks);
            asm volatile("" : "+v"(Af[m][ks]));
        }

    h16x2 b2p[4][2], w3p[4][2];
    #pragma unroll
    for (int m = 0; m < 4; ++m) {
        float4 bb = *(const float4*)(b2 + m * 16 + g * 4);
        float4 ww = *(const float4*)(w3 + m * 16 + g * 4);
        b2p[m][0] = __builtin_amdgcn_cvt_pkrtz(bb.x, bb.y);
        b2p[m][1] = __builtin_amdgcn_cvt_pkrtz(bb.z, bb.w);
        w3p[m][0] = __builtin_amdgcn_cvt_pkrtz(ww.x, ww.y);
        w3p[m][1] = __builtin_amdgcn_cvt_pkrtz(ww.z, ww.w);
    }
    float b3v = b3[0];
    int pmine = wp * 64 + lane;
    int qb = qh2 * 4;

    f16x8 qkr[2][4];
    #pragma unroll
    for (int ks = 0; ks < 4; ++ks)
        qkr[0][ks] = *(const f16x8*)(qh_s + qb * 256 + ks * 64 + g * 16);

    #pragma unroll
    for (int qq = 0; qq < 4; ++qq) {
        float zp[4];
        #pragma unroll
        for (int hh = 0; hh < 2; ++hh) {
            f32x4 C[4][2];
            #pragma unroll
            for (int ks = 0; ks < 4; ++ks) {
                f16x8 B0 = __builtin_elementwise_max(P[2 * hh + 0][ks] + qkr[qq & 1][ks], zz);
                f16x8 B1 = __builtin_elementwise_max(P[2 * hh + 1][ks] + qkr[qq & 1][ks], zz);
                #pragma unroll
                for (int m = 0; m < 4; ++m) {
                    if (ks == 0) {
                        C[m][0] = __builtin_amdgcn_mfma_f32_16x16x32_f16(Af[m][0], B0, Zv, 0, 0, 0);
                        C[m][1] = __builtin_amdgcn_mfma_f32_16x16x32_f16(Af[m][0], B1, Zv, 0, 0, 0);
                    } else {
                        C[m][0] = __builtin_amdgcn_mfma_f32_16x16x32_f16(Af[m][ks], B0, C[m][0], 0, 0, 0);
                        C[m][1] = __builtin_amdgcn_mfma_f32_16x16x32_f16(Af[m][ks], B1, C[m][1], 0, 0, 0);
                    }
                }
            }
            if (hh == 0 && qq + 1 < 4) {
                #pragma unroll
                for (int ks = 0; ks < 4; ++ks)
                    qkr[(qq + 1) & 1][ks] =
                        *(const f16x8*)(qh_s + (qb + qq + 1) * 256 + ks * 64 + g * 16);
            }
            #pragma unroll
            for (int n2 = 0; n2 < 2; ++n2) {
                float sA = 0.f, sB = 0.f;
                #pragma unroll
                for (int m = 0; m < 4; ++m) {
                    h16x2 c01 = __builtin_amdgcn_cvt_pkrtz(C[m][n2][0], C[m][n2][1]);
                    h16x2 c23 = __builtin_amdgcn_cvt_pkrtz(C[m][n2][2], C[m][n2][3]);
                    h16x2 h01 = __builtin_elementwise_max(c01 + b2p[m][0], z2);
                    h16x2 h23 = __builtin_elementwise_max(c23 + b2p[m][1], z2);
                    sA = __builtin_amdgcn_fdot2(h01, w3p[m][0], sA, false);
                    sB = __builtin_amdgcn_fdot2(h23, w3p[m][1], sB, false);
                }
                zp[2 * hh + n2] = sA + sB;
            }
        }
        float sh[4];
        #pragma unroll
        for (int i = 0; i < 4; ++i) sh[i] = __shfl_xor(zp[i], 16);
        #pragma unroll
        for (int i = 0; i < 4; ++i) zp[i] += sh[i];
        #pragma unroll
        for (int i = 0; i < 4; ++i) sh[i] = __shfl_xor(zp[i], 32);
        #pragma unroll
        for (int i = 0; i < 4; ++i) zp[i] += sh[i];

        float z = (g == 0) ? zp[0] : (g == 1) ? zp[1] : (g == 2) ? zp[2] : zp[3];
        z += b3v;
        float sp = fmaxf(z, 0.f) + __logf(1.f + __expf(-fabsf(z)));
        out[(q0 + qb + qq) * NP + pmine] = bse[qq] * (1.f + sp);   // cw ~= alpha
    }
}

extern "C" void kernel_launch(void* const* d_in, const int* in_sizes, int n_in,
                              void* d_out, int out_size, void* d_ws, size_t ws_size,
                              hipStream_t stream) {
    const float* q  = (const float*)d_in[0];
    const float* pr = (const float*)d_in[1];
    const float* W1 = (const float*)d_in[2];
    const float* b1 = (const float*)d_in[3];
    const float* W2 = (const float*)d_in[4];
    const float* b2 = (const float*)d_in[5];
    const float* W3 = (const float*)d_in[6];
    const float* b3 = (const float*)d_in[7];
    float* out = (float*)d_out;

    fused_kernel<<<NQ / 8, 512, LDS_TOTAL, stream>>>(q, pr, W1, b1, W2, b2,
                                                     W3, b3, out);
}

// Round 18
// 21.081 us; speedup vs baseline: 1.3587x; 1.0257x over previous
//
#include <hip/hip_runtime.h>
#include <hip/hip_bf16.h>
#include <hip/hip_fp16.h>

// Problem constants
#define D1   128
#define NQ   2048
#define NP   256
#define H1   128
#define H2   64

typedef __attribute__((ext_vector_type(8))) _Float16 f16x8;
typedef __attribute__((ext_vector_type(2))) __fp16   h16x2;
typedef __attribute__((ext_vector_type(4))) float    f32x4;

// LDS layout (bytes). pf16 (raw p, f16) is consumed into regs in phase 1,
// then ALIASED as ph (projected p) -- barrier-separated.
#define L_PF   0          // [256][128] f16 swz   65536 B   (later ph [p][h])
#define L_W1Q  65536      // [128][128] f16 swz   32768 B
#define L_W1P  98304      // [128][128] f16 swz   32768 B
#define L_W2   131072     // [ 64][128] f16 swz   16384 B
#define L_QF   147456     // [  8][128] f16 swz    2048 B
#define L_QH   149504     // [  8][128] f16 lin    2048 B
#define LDS_TOTAL 151552

static __device__ __forceinline__ f16x8 cvt8(float4 a, float4 b) {
    f16x8 f;
    f[0] = (_Float16)a.x; f[1] = (_Float16)a.y;
    f[2] = (_Float16)a.z; f[3] = (_Float16)a.w;
    f[4] = (_Float16)b.x; f[5] = (_Float16)b.y;
    f[6] = (_Float16)b.z; f[7] = (_Float16)b.w;
    return f;
}
static __device__ __forceinline__ float sqsum8(f16x8 v, float acc) {
    union { f16x8 f; h16x2 h[4]; } u; u.f = v;
    acc = __builtin_amdgcn_fdot2(u.h[0], u.h[0], acc, false);
    acc = __builtin_amdgcn_fdot2(u.h[1], u.h[1], acc, false);
    acc = __builtin_amdgcn_fdot2(u.h[2], u.h[2], acc, false);
    acc = __builtin_amdgcn_fdot2(u.h[3], u.h[3], acc, false);
    return acc;
}
// 16B fragment read from a 256B-row f16 LDS array, XOR-swizzled
#define FRAG(base, row, ks) \
    (*(const f16x8*)((base) + ((((row) * 256 + (ks) * 64 + g * 16)) ^ (((row) & 7) << 4))))

// ---------------------------------------------------------------------------
// ONE kernel, 512 threads, grid 256 (1 block/CU), block = 8 q x 256 p.
// Wave w: p-range (w&3)*64, q-half & h-tile-half (w>>2).
// R17 + load-hoisting (same mechanism, 3 instances):
//  (1) b1/b2/w3/b3 global loads + packing at kernel top (drained by the
//      vmcnt(0) of barrier 1 instead of stalling phase 2),
//  (2) Af LDS-frag loads right after barrier 2 (drain under proj MFMAs),
//  (3) addr precompute hoisted.
// ---------------------------------------------------------------------------
__global__ void __launch_bounds__(512, 2)
fused_kernel(const float* __restrict__ q, const float* __restrict__ p,
             const float* __restrict__ W1, const float* __restrict__ b1,
             const float* __restrict__ W2, const float* __restrict__ b2,
             const float* __restrict__ w3, const float* __restrict__ b3,
             float* __restrict__ out) {
    extern __shared__ char lds[];
    char* pf_s  = lds + L_PF;
    char* w1q_s = lds + L_W1Q;
    char* w1p_s = lds + L_W1P;
    char* w2_s  = lds + L_W2;
    char* qf_s  = lds + L_QF;
    char* qh_s  = lds + L_QH;

    int tid = threadIdx.x, lane = tid & 63, w = tid >> 6;   // w 0..7
    int lo = lane & 15, g = lane >> 4;
    int wp = w & 3, qh2 = w >> 2;
    int q0 = blockIdx.x * 8;

    // ---- hoisted: epilogue constants (global loads issued FIRST) ----
    float4 b1v = *(const float4*)(b1 + w * 16 + g * 4);
    float  b3v = b3[0];
    h16x2 b2p[4][2], w3p[4][2];
    #pragma unroll
    for (int m = 0; m < 4; ++m) {
        float4 bb = *(const float4*)(b2 + m * 16 + g * 4);
        float4 ww = *(const float4*)(w3 + m * 16 + g * 4);
        b2p[m][0] = __builtin_amdgcn_cvt_pkrtz(bb.x, bb.y);
        b2p[m][1] = __builtin_amdgcn_cvt_pkrtz(bb.z, bb.w);
        w3p[m][0] = __builtin_amdgcn_cvt_pkrtz(ww.x, ww.y);
        w3p[m][1] = __builtin_amdgcn_cvt_pkrtz(ww.z, ww.w);
    }

    // ---------------- phase 0a: stage p + q (coalesced) ----------------
    #pragma unroll
    for (int it = 0; it < 8; ++it) {        // p: [256][128] f32, 32768 f32
        int j8 = (it * 512 + tid) * 8;
        int row = j8 >> 7;
        const float* src = p + j8;
        *(f16x8*)(pf_s + ((j8 * 2) ^ ((row & 7) << 4))) =
            cvt8(*(const float4*)src, *(const float4*)(src + 4));
    }
    if (tid < 128) {                        // q rows q0..q0+7: 1024 f32
        int j8 = tid * 8;
        int row = j8 >> 7;
        const float* src = q + q0 * D1 + j8;
        *(f16x8*)(qf_s + ((j8 * 2) ^ ((row & 7) << 4))) =
            cvt8(*(const float4*)src, *(const float4*)(src + 4));
    }
    __syncthreads();                        // p, q staged (epilogue loads drained)

    // ---------------- phase 0b ∥ 1a: stage W1/W2 while computing dist ----
    #pragma unroll
    for (int it = 0; it < 8; ++it) {        // W1: [128][256] f32, split halves
        int j8 = (it * 512 + tid) * 8;
        int row = j8 >> 8, col = j8 & 255;
        const float* src = W1 + j8;
        f16x8 v = cvt8(*(const float4*)src, *(const float4*)(src + 4));
        char* base = (col < 128) ? w1q_s : w1p_s;
        *(f16x8*)(base + ((row * 256 + (col & 127) * 2) ^ ((row & 7) << 4))) = v;
    }
    #pragma unroll
    for (int it = 0; it < 2; ++it) {        // W2: [64][128] f32, 8192 f32
        int j8 = (it * 512 + tid) * 8;
        int row = j8 >> 7;
        const float* src = W2 + j8;
        *(f16x8*)(w2_s + ((j8 * 2) ^ ((row & 7) << 4))) =
            cvt8(*(const float4*)src, *(const float4*)(src + 4));
    }

    // fragment loads from already-staged p/q + norms + dist (no W1 dep)
    f16x8 Praw[4][4];
    float psq[4];
    #pragma unroll
    for (int n = 0; n < 4; ++n) {
        int prow = wp * 64 + n * 16 + lo;
        psq[n] = 0.f;
        #pragma unroll
        for (int ks = 0; ks < 4; ++ks) {
            Praw[n][ks] = FRAG(pf_s, prow, ks);
            psq[n] = sqsum8(Praw[n][ks], psq[n]);
        }
        psq[n] += __shfl_xor(psq[n], 16);
        psq[n] += __shfl_xor(psq[n], 32);   // pn[prow] on every lane
    }
    f16x8 Adist[4];
    float asq = 0.f;
    {
        int qrow = qh2 * 4 + (lo & 3);      // rows dup across g (R10 trick)
        #pragma unroll
        for (int ks = 0; ks < 4; ++ks) {
            Adist[ks] = FRAG(qf_s, qrow, ks);
            asq = sqsum8(Adist[ks], asq);
        }
        asq += __shfl_xor(asq, 16);
        asq += __shfl_xor(asq, 32);         // qn[qrow] on every lane
    }
    const f32x4 Zv = (f32x4){0.f, 0.f, 0.f, 0.f};
    const f16x8 zz = {};
    const h16x2 z2 = {};
    float bse[4];
    {   // dist: D[q][p]; lane's own p -> frag n=g
        f32x4 Cd[4];
        #pragma unroll
        for (int n = 0; n < 4; ++n) {
            Cd[n] = Zv;
            #pragma unroll
            for (int ks = 0; ks < 4; ++ks)
                Cd[n] = __builtin_amdgcn_mfma_f32_16x16x32_f16(Adist[ks], Praw[n][ks], Cd[n], 0, 0, 0);
        }
        float pnm = (g == 0) ? psq[0] : (g == 1) ? psq[1] : (g == 2) ? psq[2] : psq[3];
        #pragma unroll
        for (int qq = 0; qq < 4; ++qq) {
            float qn = __shfl(asq, qq);
            float dg = (g == 0) ? Cd[0][qq] : (g == 1) ? Cd[1][qq]
                     : (g == 2) ? Cd[2][qq] : Cd[3][qq];
            bse[qq] = fmaxf(qn + pnm - 2.f * dg, 0.f);
        }
    }
    // Bq (from qf_s, already staged) loads before the barrier
    f16x8 Bq[4];
    {
        int qrow2 = lo & 7;
        #pragma unroll
        for (int ks = 0; ks < 4; ++ks)
            Bq[ks] = FRAG(qf_s, qrow2, ks);
    }
    __syncthreads();                        // W1/W2 staged; pf reads done

    // ---- hoisted: Af frags load NOW (drain under proj MFMAs) ----
    f16x8 Af[4][4];
    #pragma unroll
    for (int m = 0; m < 4; ++m)
        #pragma unroll
        for (int ks = 0; ks < 4; ++ks) {
            Af[m][ks] = FRAG(w2_s, m * 16 + lo, ks);
            asm volatile("" : "+v"(Af[m][ks]));
        }

    // ---------------- phase 1b: q-proj, p-proj ----------------
    {   // q-proj: D[h = w*16+g*4+r][q = lo], write rows lo<8, b1 folded
        f16x8 Aq[4];
        int hrow = w * 16 + lo;
        #pragma unroll
        for (int ks = 0; ks < 4; ++ks)
            Aq[ks] = FRAG(w1q_s, hrow, ks);
        f32x4 Cq = Zv;
        #pragma unroll
        for (int ks = 0; ks < 4; ++ks)
            Cq = __builtin_amdgcn_mfma_f32_16x16x32_f16(Aq[ks], Bq[ks], Cq, 0, 0, 0);
        if (lo < 8) {
            union { h16x2 h[2]; uint2 v; } pk;
            pk.h[0] = __builtin_amdgcn_cvt_pkrtz(Cq[0] + b1v.x, Cq[1] + b1v.y);
            pk.h[1] = __builtin_amdgcn_cvt_pkrtz(Cq[2] + b1v.z, Cq[3] + b1v.w);
            *(uint2*)(qh_s + lo * 256 + w * 32 + g * 8) = pk.v;
        }
    }
    // p-proj: wave covers h-tiles qh2*4..+3 x own 4 p-tiles; write ph (=pf_s)
    #pragma unroll
    for (int hp = 0; hp < 2; ++hp) {
        f16x8 Ap[2][4];
        #pragma unroll
        for (int ht = 0; ht < 2; ++ht) {
            int h = (qh2 * 4 + hp * 2 + ht) * 16 + lo;
            #pragma unroll
            for (int ks = 0; ks < 4; ++ks)
                Ap[ht][ks] = FRAG(w1p_s, h, ks);
        }
        #pragma unroll
        for (int n = 0; n < 4; ++n) {
            f32x4 Cp0 = Zv, Cp1 = Zv;
            #pragma unroll
            for (int ks = 0; ks < 4; ++ks) {
                Cp0 = __builtin_amdgcn_mfma_f32_16x16x32_f16(Ap[0][ks], Praw[n][ks], Cp0, 0, 0, 0);
                Cp1 = __builtin_amdgcn_mfma_f32_16x16x32_f16(Ap[1][ks], Praw[n][ks], Cp1, 0, 0, 0);
            }
            int pp = wp * 64 + n * 16 + lo;
            #pragma unroll
            for (int ht = 0; ht < 2; ++ht) {
                f32x4 Cp = ht ? Cp1 : Cp0;
                int h0 = (qh2 * 4 + hp * 2 + ht) * 16 + g * 4;
                union { h16x2 h[2]; uint2 v; } pk;
                pk.h[0] = __builtin_amdgcn_cvt_pkrtz(Cp[0], Cp[1]);
                pk.h[1] = __builtin_amdgcn_cvt_pkrtz(Cp[2], Cp[3]);
                *(uint2*)(pf_s + ((pp * 256 + h0 * 2) ^ ((pp & 7) << 4))) = pk.v;
            }
        }
    }
    __syncthreads();                        // ph, qh ready

    // ---------------- phase 2: main MLP loop ----------------
    f16x8 P[4][4];
    #pragma unroll
    for (int n = 0; n < 4; ++n)
        #pragma unroll
        for (int ks = 0; ks < 4; ++ks) {
            int pp = wp * 64 + n * 16 + lo;
            P[n][ks] = FRAG(pf_s, pp, ks);
            asm volatile("" : "+v"(P[n][ks]));
        }

    int pmine = wp * 64 + lane;
    int qb = qh2 * 4;
    float* outbase = out + (q0 + qb) * NP + pmine;

    f16x8 qkr[2][4];
    const char* qhbase = qh_s + qb * 256 + g * 16;
    #pragma unroll
    for (int ks = 0; ks < 4; ++ks)
        qkr[0][ks] = *(const f16x8*)(qhbase + ks * 64);

    #pragma unroll
    for (int qq = 0; qq < 4; ++qq) {
        float zp[4];
        #pragma unroll
        for (int hh = 0; hh < 2; ++hh) {
            f32x4 C[4][2];
            #pragma unroll
            for (int ks = 0; ks < 4; ++ks) {
                f16x8 B0 = __builtin_elementwise_max(P[2 * hh + 0][ks] + qkr[qq & 1][ks], zz);
                f16x8 B1 = __builtin_elementwise_max(P[2 * hh + 1][ks] + qkr[qq & 1][ks], zz);
                #pragma unroll
                for (int m = 0; m < 4; ++m) {
                    if (ks == 0) {
                        C[m][0] = __builtin_amdgcn_mfma_f32_16x16x32_f16(Af[m][0], B0, Zv, 0, 0, 0);
                        C[m][1] = __builtin_amdgcn_mfma_f32_16x16x32_f16(Af[m][0], B1, Zv, 0, 0, 0);
                    } else {
                        C[m][0] = __builtin_amdgcn_mfma_f32_16x16x32_f16(Af[m][ks], B0, C[m][0], 0, 0, 0);
                        C[m][1] = __builtin_amdgcn_mfma_f32_16x16x32_f16(Af[m][ks], B1, C[m][1], 0, 0, 0);
                    }
                }
            }
            if (hh == 0 && qq + 1 < 4) {
                #pragma unroll
                for (int ks = 0; ks < 4; ++ks)
                    qkr[(qq + 1) & 1][ks] = *(const f16x8*)(qhbase + 256 * (qq + 1) + ks * 64);
            }
            #pragma unroll
            for (int n2 = 0; n2 < 2; ++n2) {
                float sA = 0.f, sB = 0.f;
                #pragma unroll
                for (int m = 0; m < 4; ++m) {
                    h16x2 c01 = __builtin_amdgcn_cvt_pkrtz(C[m][n2][0], C[m][n2][1]);
                    h16x2 c23 = __builtin_amdgcn_cvt_pkrtz(C[m][n2][2], C[m][n2][3]);
                    h16x2 h01 = __builtin_elementwise_max(c01 + b2p[m][0], z2);
                    h16x2 h23 = __builtin_elementwise_max(c23 + b2p[m][1], z2);
                    sA = __builtin_amdgcn_fdot2(h01, w3p[m][0], sA, false);
                    sB = __builtin_amdgcn_fdot2(h23, w3p[m][1], sB, false);
                }
                zp[2 * hh + n2] = sA + sB;
            }
        }
        float sh[4];
        #pragma unroll
        for (int i = 0; i < 4; ++i) sh[i] = __shfl_xor(zp[i], 16);
        #pragma unroll
        for (int i = 0; i < 4; ++i) zp[i] += sh[i];
        #pragma unroll
        for (int i = 0; i < 4; ++i) sh[i] = __shfl_xor(zp[i], 32);
        #pragma unroll
        for (int i = 0; i < 4; ++i) zp[i] += sh[i];

        float z = (g == 0) ? zp[0] : (g == 1) ? zp[1] : (g == 2) ? zp[2] : zp[3];
        z += b3v;
        float sp = fmaxf(z, 0.f) + __logf(1.f + __expf(-fabsf(z)));
        outbase[qq * NP] = bse[qq] * (1.f + sp);   // cw ~= alpha
    }
}

extern "C" void kernel_launch(void* const* d_in, const int* in_sizes, int n_in,
                              void* d_out, int out_size, void* d_ws, size_t ws_size,
                              hipStream_t stream) {
    const float* q  = (const float*)d_in[0];
    const float* pr = (const float*)d_in[1];
    const float* W1 = (const float*)d_in[2];
    const float* b1 = (const float*)d_in[3];
    const float* W2 = (const float*)d_in[4];
    const float* b2 = (const float*)d_in[5];
    const float* W3 = (const float*)d_in[6];
    const float* b3 = (const float*)d_in[7];
    float* out = (float*)d_out;

    fused_kernel<<<NQ / 8, 512, LDS_TOTAL, stream>>>(q, pr, W1, b1, W2, b2,
                                                     W3, b3, out);
}